// Round 7
// baseline (523.357 us; speedup 1.0000x reference)
//
#include <hip/hip_runtime.h>
#include <hip/hip_bf16.h>

#define NN 20000
#define NE 320000
#define NG 16
#define PSPLIT 32
#define NSCANB 79  // ceil(20000/256)

// ---------------- CSR build ----------------

__global__ void hist_kernel(const int* __restrict__ dst, int* __restrict__ indeg, int E) {
  int e = blockIdx.x * 256 + threadIdx.x;
  if (e < E) atomicAdd(&indeg[dst[e]], 1);
}

// hierarchical exclusive scan: per-block scan + block sums
__global__ void scan1_kernel(const int* __restrict__ in, int* __restrict__ outp,
                             int* __restrict__ bsum, int n) {
  int b = blockIdx.x, t = threadIdx.x;
  int i = b * 256 + t;
  int lane = t & 63, wv = t >> 6;
  __shared__ int ws[4];
  int v = (i < n) ? in[i] : 0;
  int x = v;
#pragma unroll
  for (int off = 1; off < 64; off <<= 1) {
    int y = __shfl_up(x, off);
    if (lane >= off) x += y;
  }
  if (lane == 63) ws[wv] = x;
  __syncthreads();
  int add = 0;
  for (int w2 = 0; w2 < wv; w2++) add += ws[w2];
  x += add;
  if (i < n) outp[i] = x - v;  // block-local exclusive
  if (t == 255) bsum[b] = x;   // block total
}

// scan block sums (nb <= 128), write offsets + grand total to rowptr[NN]
__global__ void scan2_kernel(const int* __restrict__ bsum, int* __restrict__ boff,
                             int* __restrict__ rp_end, int nb) {
  int t = threadIdx.x;  // 128
  int lane = t & 63, wv = t >> 6;
  __shared__ int ws[2];
  int v = (t < nb) ? bsum[t] : 0;
  int x = v;
#pragma unroll
  for (int off = 1; off < 64; off <<= 1) {
    int y = __shfl_up(x, off);
    if (lane >= off) x += y;
  }
  if (lane == 63) ws[wv] = x;
  __syncthreads();
  if (wv == 1) x += ws[0];
  if (t < nb) boff[t] = x - v;
  if (t == 127) *rp_end = x;
}

__global__ void scan3_kernel(int* __restrict__ outp, const int* __restrict__ boff, int n) {
  int i = blockIdx.x * 256 + threadIdx.x;
  if (i < n) outp[i] += boff[blockIdx.x];
}

__global__ void scatter_kernel(const int* __restrict__ src, const int* __restrict__ dst,
                               const int* __restrict__ rowptr, int* __restrict__ cursor,
                               int* __restrict__ csr_src, int E) {
  int e = blockIdx.x * 256 + threadIdx.x;
  if (e < E) {
    int d = dst[e];
    int p = atomicAdd(&cursor[d], 1);
    csr_src[rowptr[d] + p] = src[e];
  }
}

// ---------------- layer-1 attention vectors pushed through W1 ----------------

__global__ void prep_wlr_kernel(const float* __restrict__ W1, const float* __restrict__ al1,
                                const float* __restrict__ ar1, float* __restrict__ wlr) {
  int t = blockIdx.x * 256 + threadIdx.x;  // 768 total
  if (t >= 768) return;
  int k = t & 127;
  int j = t >> 7;  // 0..5
  int h = j % 3;
  const float* av = (j < 3 ? al1 : ar1) + h * 128;
  const float* wrow = W1 + (size_t)k * 384 + h * 128;
  float s = 0.f;
#pragma unroll 4
  for (int d = 0; d < 128; d++) s += wrow[d] * av[d];
  wlr[j * 128 + k] = s;
}

// el1/er1 for all nodes: one wave per node
__global__ void elr_kernel(const float* __restrict__ x, const float* __restrict__ wlr,
                           float* __restrict__ el, float* __restrict__ er, int N) {
  __shared__ float wl_s[768];
  int t = threadIdx.x;
  for (int i = t; i < 768; i += 256) wl_s[i] = wlr[i];
  __syncthreads();
  int w = (blockIdx.x * 256 + t) >> 6;
  int lane = t & 63;
  if (w >= N) return;
  float v0 = x[(size_t)w * 128 + lane], v1 = x[(size_t)w * 128 + 64 + lane];
  float s[6];
#pragma unroll
  for (int j = 0; j < 6; j++) s[j] = v0 * wl_s[j * 128 + lane] + v1 * wl_s[j * 128 + 64 + lane];
#pragma unroll
  for (int off = 32; off; off >>= 1)
#pragma unroll
    for (int j = 0; j < 6; j++) s[j] += __shfl_down(s[j], off);
  if (lane == 0) {
    el[w * 3 + 0] = s[0]; el[w * 3 + 1] = s[1]; el[w * 3 + 2] = s[2];
    er[w * 3 + 0] = s[3]; er[w * 3 + 1] = s[4]; er[w * 3 + 2] = s[5];
  }
}

// ---------------- layer-1 aggregation in x-space ----------------

__global__ void aggregate_x_kernel(const float* __restrict__ x, const float* __restrict__ el,
                                   const float* __restrict__ er, const int* __restrict__ rowptr,
                                   const int* __restrict__ csr_src, float* __restrict__ aggx) {
  int n = blockIdx.x;
  int t = threadIdx.x;  // 128
  __shared__ float wbuf[3][128];
  __shared__ int sbuf[128];
  __shared__ float red[6];
  __shared__ float4 accbuf[3][4][32];
  int rs = rowptr[n];
  int deg = rowptr[n + 1] - rs;
  float er0 = er[n * 3 + 0], er1 = er[n * 3 + 1], er2 = er[n * 3 + 2];
  float p0 = 0.f, p1 = 0.f, p2 = 0.f;
  int g = t >> 5, dq = t & 31;
  const float* xd = x + dq * 4;
  float4 a0 = make_float4(0, 0, 0, 0), a1 = a0, a2 = a0;
  for (int base = 0; base < deg; base += 128) {
    int cnt = min(128, deg - base);
    if (t < cnt) {
      int s = csr_src[rs + base + t];
      sbuf[t] = s;
      float e0 = el[s * 3 + 0] + er0, e1 = el[s * 3 + 1] + er1, e2 = el[s * 3 + 2] + er2;
      e0 = e0 > 0.f ? e0 : 0.2f * e0;
      e1 = e1 > 0.f ? e1 : 0.2f * e1;
      e2 = e2 > 0.f ? e2 : 0.2f * e2;
      float w0 = __expf(e0), w1 = __expf(e1), w2 = __expf(e2);
      wbuf[0][t] = w0; wbuf[1][t] = w1; wbuf[2][t] = w2;
      p0 += w0; p1 += w1; p2 += w2;
    }
    __syncthreads();
    int j = g;
    for (; j + 4 < cnt; j += 8) {
      int s0 = sbuf[j], s1 = sbuf[j + 4];
      float4 v0 = *(const float4*)(xd + (size_t)s0 * 128);
      float4 v1 = *(const float4*)(xd + (size_t)s1 * 128);
      float w00 = wbuf[0][j], w01 = wbuf[1][j], w02 = wbuf[2][j];
      float w10 = wbuf[0][j + 4], w11 = wbuf[1][j + 4], w12 = wbuf[2][j + 4];
      a0.x += w00 * v0.x + w10 * v1.x; a0.y += w00 * v0.y + w10 * v1.y;
      a0.z += w00 * v0.z + w10 * v1.z; a0.w += w00 * v0.w + w10 * v1.w;
      a1.x += w01 * v0.x + w11 * v1.x; a1.y += w01 * v0.y + w11 * v1.y;
      a1.z += w01 * v0.z + w11 * v1.z; a1.w += w01 * v0.w + w11 * v1.w;
      a2.x += w02 * v0.x + w12 * v1.x; a2.y += w02 * v0.y + w12 * v1.y;
      a2.z += w02 * v0.z + w12 * v1.z; a2.w += w02 * v0.w + w12 * v1.w;
    }
    for (; j < cnt; j += 4) {
      int s = sbuf[j];
      float4 v = *(const float4*)(xd + (size_t)s * 128);
      float w0 = wbuf[0][j], w1 = wbuf[1][j], w2 = wbuf[2][j];
      a0.x += w0 * v.x; a0.y += w0 * v.y; a0.z += w0 * v.z; a0.w += w0 * v.w;
      a1.x += w1 * v.x; a1.y += w1 * v.y; a1.z += w1 * v.z; a1.w += w1 * v.w;
      a2.x += w2 * v.x; a2.y += w2 * v.y; a2.z += w2 * v.z; a2.w += w2 * v.w;
    }
    __syncthreads();
  }
  for (int off = 32; off; off >>= 1) {
    p0 += __shfl_down(p0, off);
    p1 += __shfl_down(p1, off);
    p2 += __shfl_down(p2, off);
  }
  int wv = t >> 6, ln = t & 63;
  if (ln == 0) { red[wv * 3 + 0] = p0; red[wv * 3 + 1] = p1; red[wv * 3 + 2] = p2; }
  accbuf[0][g][dq] = a0;
  accbuf[1][g][dq] = a1;
  accbuf[2][g][dq] = a2;
  __syncthreads();
  if (t < 96) {
    int h = t >> 5, d = t & 31;
    float4 s0 = accbuf[h][0][d], s1 = accbuf[h][1][d], s2 = accbuf[h][2][d], s3 = accbuf[h][3][d];
    float dn = red[h] + red[3 + h];
    float inv = dn > 0.f ? 1.f / dn : 0.f;
    float4 r;
    r.x = (s0.x + s1.x + s2.x + s3.x) * inv;
    r.y = (s0.y + s1.y + s2.y + s3.y) * inv;
    r.z = (s0.z + s1.z + s2.z + s3.z) * inv;
    r.w = (s0.w + s1.w + s2.w + s3.w) * inv;
    *(float4*)&aggx[(size_t)n * 384 + h * 128 + d * 4] = r;
  }
}

// ---------------- GEMM: 128x128 tile, 256 threads, 8x8 microtile,
// ping-pong double buffer at 16-k half-tile granularity ----------------
// Round-5 post-mortem: 1 B LDS per FMA, ds_read_b128 throughput ~85 B/cy (m134)
// -> LDS-bus ceiling ~66% VALU; measured 45% because the single-buffer
// stage->barrier->compute loop exposes ds_write + barrier drain every tile.
// This version: per 16-k half: compute(buf c) -> write buf c^1 (regs loaded one
// half earlier; vmcnt satisfied) -> issue loads h+2 -> barrier. Same 8 barriers
// per K=128, zero exposed global latency (loads lead by ~4096 cyc >> 900-cyc HBM).
// Resubmitted unchanged after round-6 abort: full static audit (LDS<=511 both
// arrays, global reads/writes at-but-within boundaries, XOR layout round-trips,
// no cross-buffer race across barriers, swizzle bijective at NWG=471) found no
// fault; treating the core dump as a node flake (round-4 precedent).
// LDS 32 KB total:
//   Asb[buf][r*4 + (qh^(r&3))] float4 = A[row r][qh*4..+3] of the half.
//   Bsb[buf][k*32+n4] float4 = B[k][n4*4..+3].
// SPLIT (GEMM2): K-split x3 over cb; GEMM1: cb = head/col-block.

template <int NCB, bool SPLIT, bool BIAS_ELU>
__launch_bounds__(256, 2)
__global__ void gemm_dbuf_kernel(const float* __restrict__ A, int lda,
                                 const float* __restrict__ B, int ldb,
                                 float* __restrict__ C, int ldc,
                                 const float* __restrict__ bias) {
  __shared__ float4 Asb[2][128 * 4];  // 16 KB
  __shared__ float4 Bsb[2][16 * 32];  // 16 KB
  int t = threadIdx.x;
  int tm = t >> 4, tn = t & 15;

  // bijective XCD-chunk swizzle: consecutive logical tiles -> same XCD L2.
  constexpr int NROWT = 157;  // ceil(20000/128)
  constexpr int NWG = NROWT * NCB;
  constexpr int QW = NWG >> 3, RW = NWG & 7;
  int o = blockIdx.x;
  int xcd = o & 7, i8 = o >> 3;
  int wgid = (xcd < RW ? xcd * (QW + 1) : RW * (QW + 1) + (xcd - RW) * QW) + i8;
  int rt = wgid / NCB, cb = wgid - rt * NCB;
  int m0 = rt * 128;

  const float* Ab = A + (size_t)(cb * 128);
  const float* Bb = SPLIT ? B + (size_t)(cb * 128) * ldb : B + cb * 128;
  float* Cb = SPLIT ? C + (size_t)cb * NN * ldc : C + cb * 128;

  // staging geometry (fixed; k-offset advances per half)
  const float* sA[2];
  int dA[2];
#pragma unroll
  for (int p = 0; p < 2; ++p) {
    int idx = p * 256 + t;
    int r = idx >> 2, qh = idx & 3;
    int row = m0 + r;
    if (row >= NN) row = NN - 1;  // tail tile: clamp (stores guarded)
    sA[p] = Ab + (size_t)row * lda + qh * 4;
    dA[p] = r * 4 + (qh ^ (r & 3));
  }
  const float* sB[2];
  int dB[2];
#pragma unroll
  for (int p = 0; p < 2; ++p) {
    int idx = p * 256 + t;
    int kk = idx >> 5, n4 = idx & 31;
    sB[p] = Bb + (size_t)kk * ldb + n4 * 4;
    dB[p] = kk * 32 + n4;
  }

  float acc[8][8];
#pragma unroll
  for (int i = 0; i < 8; ++i)
#pragma unroll
    for (int c = 0; c < 8; ++c) acc[i][c] = 0.f;

  // prologue: half 0 -> LDS[0]; issue half-1 loads
  float4 pa[2], pb[2];
#pragma unroll
  for (int p = 0; p < 2; ++p) { pa[p] = *(const float4*)sA[p]; pb[p] = *(const float4*)sB[p]; }
#pragma unroll
  for (int p = 0; p < 2; ++p) { Asb[0][dA[p]] = pa[p]; Bsb[0][dB[p]] = pb[p]; }
  __syncthreads();
#pragma unroll
  for (int p = 0; p < 2; ++p) {
    pa[p] = *(const float4*)(sA[p] + 16);
    pb[p] = *(const float4*)(sB[p] + (size_t)16 * ldb);
  }

  for (int h = 0; h < 8; ++h) {  // 8 half-tiles of 16 k = K:128
    int c = h & 1;
#pragma unroll
    for (int qh = 0; qh < 4; ++qh) {
      float4 fa[8];
#pragma unroll
      for (int i = 0; i < 8; ++i)
        fa[i] = Asb[c][(tm + 16 * i) * 4 + (qh ^ (tm & 3))];
#pragma unroll
      for (int j = 0; j < 4; ++j) {
        int kk = qh * 4 + j;
        float4 b0 = Bsb[c][kk * 32 + tn];
        float4 b1 = Bsb[c][kk * 32 + 16 + tn];
#pragma unroll
        for (int i = 0; i < 8; ++i) {
          float a = (j == 0) ? fa[i].x : (j == 1) ? fa[i].y : (j == 2) ? fa[i].z : fa[i].w;
          acc[i][0] += a * b0.x; acc[i][1] += a * b0.y;
          acc[i][2] += a * b0.z; acc[i][3] += a * b0.w;
          acc[i][4] += a * b1.x; acc[i][5] += a * b1.y;
          acc[i][6] += a * b1.z; acc[i][7] += a * b1.w;
        }
      }
    }
    if (h + 1 < 8) {  // write next half (regs loaded one half earlier)
#pragma unroll
      for (int p = 0; p < 2; ++p) { Asb[c ^ 1][dA[p]] = pa[p]; Bsb[c ^ 1][dB[p]] = pb[p]; }
    }
    if (h + 2 < 8) {  // issue loads two halves ahead
      int ko = (h + 2) * 16;
#pragma unroll
      for (int p = 0; p < 2; ++p) {
        pa[p] = *(const float4*)(sA[p] + ko);
        pb[p] = *(const float4*)(sB[p] + (size_t)ko * ldb);
      }
    }
    __syncthreads();
  }

  const float* bp0 = bias ? bias + cb * 128 + tn * 4 : nullptr;
#pragma unroll
  for (int i = 0; i < 8; ++i) {
    int row = m0 + tm + 16 * i;
    if (row < NN) {
      float* Cr = Cb + (size_t)row * ldc + tn * 4;
      float4 v0 = make_float4(acc[i][0], acc[i][1], acc[i][2], acc[i][3]);
      float4 v1 = make_float4(acc[i][4], acc[i][5], acc[i][6], acc[i][7]);
      if (BIAS_ELU) {
        v0.x += bp0[0]; v0.y += bp0[1]; v0.z += bp0[2]; v0.w += bp0[3];
        v1.x += bp0[64]; v1.y += bp0[65]; v1.z += bp0[66]; v1.w += bp0[67];
        v0.x = v0.x > 0.f ? v0.x : expm1f(v0.x);
        v0.y = v0.y > 0.f ? v0.y : expm1f(v0.y);
        v0.z = v0.z > 0.f ? v0.z : expm1f(v0.z);
        v0.w = v0.w > 0.f ? v0.w : expm1f(v0.w);
        v1.x = v1.x > 0.f ? v1.x : expm1f(v1.x);
        v1.y = v1.y > 0.f ? v1.y : expm1f(v1.y);
        v1.z = v1.z > 0.f ? v1.z : expm1f(v1.z);
        v1.w = v1.w > 0.f ? v1.w : expm1f(v1.w);
      }
      *(float4*)Cr = v0;
      *(float4*)(Cr + 64) = v1;
    }
  }
}

// ---------------- combine K-split partials + attention coefficients (layer 2) ----

__global__ void att_combine_kernel(const float* __restrict__ fp, const float* __restrict__ al,
                                   const float* __restrict__ ar, float* __restrict__ f2,
                                   float* __restrict__ el, float* __restrict__ er, int N) {
  int w = (blockIdx.x * 256 + threadIdx.x) >> 6;
  int lane = threadIdx.x & 63;
  if (w >= N) return;
  size_t base = (size_t)w * 128;
  const size_t PS = (size_t)NN * 128;
  float v0 = fp[base + lane] + fp[PS + base + lane] + fp[2 * PS + base + lane];
  float v1 = fp[base + 64 + lane] + fp[PS + base + 64 + lane] + fp[2 * PS + base + 64 + lane];
  f2[base + lane] = v0;
  f2[base + 64 + lane] = v1;
  float se = v0 * al[lane] + v1 * al[64 + lane];
  float sr = v0 * ar[lane] + v1 * ar[64 + lane];
  for (int off = 32; off; off >>= 1) {
    se += __shfl_down(se, off);
    sr += __shfl_down(sr, off);
  }
  if (lane == 0) { el[w] = se; er[w] = sr; }
}

// ---------------- layer-2 aggregation (H=1, gathers f2) ----------------

__global__ void aggregate1_kernel(const float* __restrict__ f, const float* __restrict__ el,
                                  const float* __restrict__ er, const float* __restrict__ bias,
                                  const int* __restrict__ rowptr, const int* __restrict__ csr_src,
                                  float* __restrict__ out) {
  int n = blockIdx.x;
  int t = threadIdx.x;
  __shared__ float wbuf[128];
  __shared__ int sbuf[128];
  __shared__ float red[2];
  __shared__ float4 accbuf[4][32];
  int rs = rowptr[n];
  int deg = rowptr[n + 1] - rs;
  float ern = er[n];
  float psum = 0.f;
  int g = t >> 5;
  int d = (t & 31) * 4;
  const float* fd = f + d;
  float4 acc = make_float4(0.f, 0.f, 0.f, 0.f);
  for (int base = 0; base < deg; base += 128) {
    int cnt = min(128, deg - base);
    if (t < cnt) {
      int s = csr_src[rs + base + t];
      sbuf[t] = s;
      float e = el[s] + ern;
      e = e > 0.f ? e : 0.2f * e;
      float w = __expf(e);
      wbuf[t] = w;
      psum += w;
    }
    __syncthreads();
    int j = g;
    for (; j + 4 < cnt; j += 8) {
      int s0 = sbuf[j], s1 = sbuf[j + 4];
      float4 v0 = *(const float4*)(fd + (size_t)s0 * 128);
      float4 v1 = *(const float4*)(fd + (size_t)s1 * 128);
      float w0 = wbuf[j], w1 = wbuf[j + 4];
      acc.x += w0 * v0.x + w1 * v1.x;
      acc.y += w0 * v0.y + w1 * v1.y;
      acc.z += w0 * v0.z + w1 * v1.z;
      acc.w += w0 * v0.w + w1 * v1.w;
    }
    for (; j < cnt; j += 4) {
      int s = sbuf[j];
      float4 v = *(const float4*)(fd + (size_t)s * 128);
      float w = wbuf[j];
      acc.x += w * v.x; acc.y += w * v.y; acc.z += w * v.z; acc.w += w * v.w;
    }
    __syncthreads();
  }
  for (int off = 32; off; off >>= 1) psum += __shfl_down(psum, off);
  int wv = t >> 6, ln = t & 63;
  if (ln == 0) red[wv] = psum;
  accbuf[g][t & 31] = acc;
  __syncthreads();
  if (t < 32) {
    float4 a0 = accbuf[0][t], a1 = accbuf[1][t], a2 = accbuf[2][t], a3 = accbuf[3][t];
    float dn = red[0] + red[1];
    float inv = dn > 0.f ? 1.f / dn : 0.f;
    const float* bp = bias + t * 4;
    float4 r;
    r.x = (a0.x + a1.x + a2.x + a3.x) * inv + bp[0];
    r.y = (a0.y + a1.y + a2.y + a3.y) * inv + bp[1];
    r.z = (a0.z + a1.z + a2.z + a3.z) * inv + bp[2];
    r.w = (a0.w + a1.w + a2.w + a3.w) * inv + bp[3];
    *(float4*)&out[(size_t)n * 128 + t * 4] = r;
  }
}

// ---------------- mean-pool: 2-stage ----------------

__global__ void pool_partial_kernel(const float* __restrict__ h2, const int* __restrict__ gid,
                                    float* __restrict__ sums, int N) {
  int g = blockIdx.x / PSPLIT;
  int sp = blockIdx.x % PSPLIT;
  int tid = threadIdx.x;
  int lo0 = 0, hi0 = N;
  while (lo0 < hi0) { int m = (lo0 + hi0) >> 1; if (gid[m] < g) lo0 = m + 1; else hi0 = m; }
  int lo1 = lo0, hi1 = N;
  while (lo1 < hi1) { int m = (lo1 + hi1) >> 1; if (gid[m] < g + 1) lo1 = m + 1; else hi1 = m; }
  float a0 = 0.f, a1 = 0.f, a2 = 0.f, a3 = 0.f;
  int n = lo0 + sp;
  for (; n + 3 * PSPLIT < lo1; n += 4 * PSPLIT) {
    a0 += h2[(size_t)n * 128 + tid];
    a1 += h2[(size_t)(n + PSPLIT) * 128 + tid];
    a2 += h2[(size_t)(n + 2 * PSPLIT) * 128 + tid];
    a3 += h2[(size_t)(n + 3 * PSPLIT) * 128 + tid];
  }
  for (; n < lo1; n += PSPLIT) a0 += h2[(size_t)n * 128 + tid];
  float acc = (a0 + a1) + (a2 + a3);
  atomicAdd(&sums[g * 128 + tid], acc);
}

__global__ void pool_final_kernel(const float* __restrict__ sums, const int* __restrict__ gid,
                                  const float* __restrict__ linW, const float* __restrict__ linb,
                                  float* __restrict__ out, int N) {
  int g = blockIdx.x;
  int tid = threadIdx.x;
  int lo0 = 0, hi0 = N;
  while (lo0 < hi0) { int m = (lo0 + hi0) >> 1; if (gid[m] < g) lo0 = m + 1; else hi0 = m; }
  int lo1 = lo0, hi1 = N;
  while (lo1 < hi1) { int m = (lo1 + hi1) >> 1; if (gid[m] < g + 1) lo1 = m + 1; else hi1 = m; }
  int cnt = lo1 - lo0;
  float hg = sums[g * 128 + tid] / (float)(cnt > 0 ? cnt : 1);
  __shared__ float hgs[128];
  hgs[tid] = hg;
  __syncthreads();
  float o = linb[tid];
#pragma unroll 4
  for (int dd = 0; dd < 128; dd++) o += hgs[dd] * linW[dd * 128 + tid];
  out[g * 128 + tid] = fmaxf(o, 0.f);
}

// ---------------- launch ----------------

extern "C" void kernel_launch(void* const* d_in, const int* in_sizes, int n_in,
                              void* d_out, int out_size, void* d_ws, size_t ws_size,
                              hipStream_t stream) {
  const float* x    = (const float*)d_in[0];
  const int*   src  = (const int*)d_in[1];
  const int*   dst  = (const int*)d_in[2];
  const int*   gid  = (const int*)d_in[3];
  const float* W1   = (const float*)d_in[4];
  const float* al1  = (const float*)d_in[5];
  const float* ar1  = (const float*)d_in[6];
  const float* b1   = (const float*)d_in[7];
  const float* W2   = (const float*)d_in[8];
  const float* al2  = (const float*)d_in[9];
  const float* ar2  = (const float*)d_in[10];
  const float* b2   = (const float*)d_in[11];
  const float* linW = (const float*)d_in[12];
  const float* linb = (const float*)d_in[13];
  float* out = (float*)d_out;

  char* ws = (char*)d_ws;
  size_t off = 0;
  auto alloc = [&](size_t bytes) -> void* {
    void* p = ws + off;
    off += (bytes + 255) & ~(size_t)255;
    return p;
  };
  float* aggx    = (float*)alloc((size_t)NN * 384 * 4);  // reused as fpart (3x NN*128) after GEMM1
  float* h1      = (float*)alloc((size_t)NN * 384 * 4);
  float* f2      = (float*)alloc((size_t)NN * 128 * 4);
  float* h2      = (float*)alloc((size_t)NN * 128 * 4);
  float* el1     = (float*)alloc((size_t)NN * 3 * 4);
  float* er1     = (float*)alloc((size_t)NN * 3 * 4);
  float* el2     = (float*)alloc((size_t)NN * 4);
  float* er2     = (float*)alloc((size_t)NN * 4);
  float* wlr     = (float*)alloc((size_t)768 * 4);
  int*   rowptr  = (int*)alloc((size_t)(NN + 1) * 4);
  int*   csr_src = (int*)alloc((size_t)NE * 4);
  int*   bsum    = (int*)alloc((size_t)NSCANB * 4);
  int*   boff    = (int*)alloc((size_t)NSCANB * 4);
  // zero-initialized region (single memset): indeg, cursor, gsums
  int*   indeg   = (int*)alloc((size_t)NN * 4);
  int*   cursor  = (int*)alloc((size_t)NN * 4);
  float* gsums   = (float*)alloc((size_t)NG * 128 * 4);
  (void)ws_size;
  size_t zbytes = (char*)(gsums + NG * 128) - (char*)indeg;
  hipMemsetAsync(indeg, 0, zbytes, stream);

  // CSR build (hierarchical scan)
  hist_kernel<<<(NE + 255) / 256, 256, 0, stream>>>(dst, indeg, NE);
  scan1_kernel<<<NSCANB, 256, 0, stream>>>(indeg, rowptr, bsum, NN);
  scan2_kernel<<<1, 128, 0, stream>>>(bsum, boff, rowptr + NN, NSCANB);
  scan3_kernel<<<NSCANB, 256, 0, stream>>>(rowptr, boff, NN);
  scatter_kernel<<<(NE + 255) / 256, 256, 0, stream>>>(src, dst, rowptr, cursor, csr_src, NE);

  // Layer 1 (x-space): wlr -> el/er -> aggregate x -> per-head GEMM with bias+ELU
  prep_wlr_kernel<<<3, 256, 0, stream>>>(W1, al1, ar1, wlr);
  elr_kernel<<<(NN + 3) / 4, 256, 0, stream>>>(x, wlr, el1, er1, NN);
  aggregate_x_kernel<<<NN, 128, 0, stream>>>(x, el1, er1, rowptr, csr_src, aggx);
  gemm_dbuf_kernel<3, false, true><<<157 * 3, 256, 0, stream>>>(
      aggx, 384, W1, 384, h1, 384, b1);

  // Layer 2: f2 = h1 @ W2 via K-split x3 (partials into fpart = reused aggx),
  // combined + el2/er2 in att_combine; aggregate(+b2) -> h2
  float* fpart = aggx;  // aggx dead after GEMM1; 3 * NN*128 floats fits exactly
  gemm_dbuf_kernel<3, true, false><<<157 * 3, 256, 0, stream>>>(
      h1, 384, W2, 128, fpart, 128, nullptr);
  att_combine_kernel<<<(NN + 3) / 4, 256, 0, stream>>>(fpart, al2, ar2, f2, el2, er2, NN);
  aggregate1_kernel<<<NN, 128, 0, stream>>>(f2, el2, er2, b2, rowptr, csr_src, h2);

  // Mean-pool + linear head
  pool_partial_kernel<<<NG * PSPLIT, 128, 0, stream>>>(h2, gid, gsums, NN);
  pool_final_kernel<<<NG, 128, 0, stream>>>(gsums, gid, linW, linb, out, NN);
}

// Round 8
// 312.964 us; speedup vs baseline: 1.6723x; 1.6723x over previous
//
#include <hip/hip_runtime.h>
#include <hip/hip_bf16.h>

#define NN 20000
#define NE 320000
#define NG 16
#define PSPLIT 32
#define NSCANB 79  // ceil(20000/256)

// ---------------- CSR build ----------------

__global__ void hist_kernel(const int* __restrict__ dst, int* __restrict__ indeg, int E) {
  int e = blockIdx.x * 256 + threadIdx.x;
  if (e < E) atomicAdd(&indeg[dst[e]], 1);
}

// hierarchical exclusive scan: per-block scan + block sums
__global__ void scan1_kernel(const int* __restrict__ in, int* __restrict__ outp,
                             int* __restrict__ bsum, int n) {
  int b = blockIdx.x, t = threadIdx.x;
  int i = b * 256 + t;
  int lane = t & 63, wv = t >> 6;
  __shared__ int ws[4];
  int v = (i < n) ? in[i] : 0;
  int x = v;
#pragma unroll
  for (int off = 1; off < 64; off <<= 1) {
    int y = __shfl_up(x, off);
    if (lane >= off) x += y;
  }
  if (lane == 63) ws[wv] = x;
  __syncthreads();
  int add = 0;
  for (int w2 = 0; w2 < wv; w2++) add += ws[w2];
  x += add;
  if (i < n) outp[i] = x - v;  // block-local exclusive
  if (t == 255) bsum[b] = x;   // block total
}

// scan block sums (nb <= 128), write offsets + grand total to rowptr[NN]
__global__ void scan2_kernel(const int* __restrict__ bsum, int* __restrict__ boff,
                             int* __restrict__ rp_end, int nb) {
  int t = threadIdx.x;  // 128
  int lane = t & 63, wv = t >> 6;
  __shared__ int ws[2];
  int v = (t < nb) ? bsum[t] : 0;
  int x = v;
#pragma unroll
  for (int off = 1; off < 64; off <<= 1) {
    int y = __shfl_up(x, off);
    if (lane >= off) x += y;
  }
  if (lane == 63) ws[wv] = x;
  __syncthreads();
  if (wv == 1) x += ws[0];
  if (t < nb) boff[t] = x - v;
  if (t == 127) *rp_end = x;
}

__global__ void scan3_kernel(int* __restrict__ outp, const int* __restrict__ boff, int n) {
  int i = blockIdx.x * 256 + threadIdx.x;
  if (i < n) outp[i] += boff[blockIdx.x];
}

__global__ void scatter_kernel(const int* __restrict__ src, const int* __restrict__ dst,
                               const int* __restrict__ rowptr, int* __restrict__ cursor,
                               int* __restrict__ csr_src, int E) {
  int e = blockIdx.x * 256 + threadIdx.x;
  if (e < E) {
    int d = dst[e];
    int p = atomicAdd(&cursor[d], 1);
    csr_src[rowptr[d] + p] = src[e];
  }
}

// ---------------- layer-1 attention vectors pushed through W1 ----------------

__global__ void prep_wlr_kernel(const float* __restrict__ W1, const float* __restrict__ al1,
                                const float* __restrict__ ar1, float* __restrict__ wlr) {
  int t = blockIdx.x * 256 + threadIdx.x;  // 768 total
  if (t >= 768) return;
  int k = t & 127;
  int j = t >> 7;  // 0..5
  int h = j % 3;
  const float* av = (j < 3 ? al1 : ar1) + h * 128;
  const float* wrow = W1 + (size_t)k * 384 + h * 128;
  float s = 0.f;
#pragma unroll 4
  for (int d = 0; d < 128; d++) s += wrow[d] * av[d];
  wlr[j * 128 + k] = s;
}

// el1/er1 for all nodes: one wave per node
__global__ void elr_kernel(const float* __restrict__ x, const float* __restrict__ wlr,
                           float* __restrict__ el, float* __restrict__ er, int N) {
  __shared__ float wl_s[768];
  int t = threadIdx.x;
  for (int i = t; i < 768; i += 256) wl_s[i] = wlr[i];
  __syncthreads();
  int w = (blockIdx.x * 256 + t) >> 6;
  int lane = t & 63;
  if (w >= N) return;
  float v0 = x[(size_t)w * 128 + lane], v1 = x[(size_t)w * 128 + 64 + lane];
  float s[6];
#pragma unroll
  for (int j = 0; j < 6; j++) s[j] = v0 * wl_s[j * 128 + lane] + v1 * wl_s[j * 128 + 64 + lane];
#pragma unroll
  for (int off = 32; off; off >>= 1)
#pragma unroll
    for (int j = 0; j < 6; j++) s[j] += __shfl_down(s[j], off);
  if (lane == 0) {
    el[w * 3 + 0] = s[0]; el[w * 3 + 1] = s[1]; el[w * 3 + 2] = s[2];
    er[w * 3 + 0] = s[3]; er[w * 3 + 1] = s[4]; er[w * 3 + 2] = s[5];
  }
}

// ---------------- layer-1 aggregation in x-space ----------------

__global__ void aggregate_x_kernel(const float* __restrict__ x, const float* __restrict__ el,
                                   const float* __restrict__ er, const int* __restrict__ rowptr,
                                   const int* __restrict__ csr_src, float* __restrict__ aggx) {
  int n = blockIdx.x;
  int t = threadIdx.x;  // 128
  __shared__ float wbuf[3][128];
  __shared__ int sbuf[128];
  __shared__ float red[6];
  __shared__ float4 accbuf[3][4][32];
  int rs = rowptr[n];
  int deg = rowptr[n + 1] - rs;
  float er0 = er[n * 3 + 0], er1 = er[n * 3 + 1], er2 = er[n * 3 + 2];
  float p0 = 0.f, p1 = 0.f, p2 = 0.f;
  int g = t >> 5, dq = t & 31;
  const float* xd = x + dq * 4;
  float4 a0 = make_float4(0, 0, 0, 0), a1 = a0, a2 = a0;
  for (int base = 0; base < deg; base += 128) {
    int cnt = min(128, deg - base);
    if (t < cnt) {
      int s = csr_src[rs + base + t];
      sbuf[t] = s;
      float e0 = el[s * 3 + 0] + er0, e1 = el[s * 3 + 1] + er1, e2 = el[s * 3 + 2] + er2;
      e0 = e0 > 0.f ? e0 : 0.2f * e0;
      e1 = e1 > 0.f ? e1 : 0.2f * e1;
      e2 = e2 > 0.f ? e2 : 0.2f * e2;
      float w0 = __expf(e0), w1 = __expf(e1), w2 = __expf(e2);
      wbuf[0][t] = w0; wbuf[1][t] = w1; wbuf[2][t] = w2;
      p0 += w0; p1 += w1; p2 += w2;
    }
    __syncthreads();
    int j = g;
    for (; j + 4 < cnt; j += 8) {
      int s0 = sbuf[j], s1 = sbuf[j + 4];
      float4 v0 = *(const float4*)(xd + (size_t)s0 * 128);
      float4 v1 = *(const float4*)(xd + (size_t)s1 * 128);
      float w00 = wbuf[0][j], w01 = wbuf[1][j], w02 = wbuf[2][j];
      float w10 = wbuf[0][j + 4], w11 = wbuf[1][j + 4], w12 = wbuf[2][j + 4];
      a0.x += w00 * v0.x + w10 * v1.x; a0.y += w00 * v0.y + w10 * v1.y;
      a0.z += w00 * v0.z + w10 * v1.z; a0.w += w00 * v0.w + w10 * v1.w;
      a1.x += w01 * v0.x + w11 * v1.x; a1.y += w01 * v0.y + w11 * v1.y;
      a1.z += w01 * v0.z + w11 * v1.z; a1.w += w01 * v0.w + w11 * v1.w;
      a2.x += w02 * v0.x + w12 * v1.x; a2.y += w02 * v0.y + w12 * v1.y;
      a2.z += w02 * v0.z + w12 * v1.z; a2.w += w02 * v0.w + w12 * v1.w;
    }
    for (; j < cnt; j += 4) {
      int s = sbuf[j];
      float4 v = *(const float4*)(xd + (size_t)s * 128);
      float w0 = wbuf[0][j], w1 = wbuf[1][j], w2 = wbuf[2][j];
      a0.x += w0 * v.x; a0.y += w0 * v.y; a0.z += w0 * v.z; a0.w += w0 * v.w;
      a1.x += w1 * v.x; a1.y += w1 * v.y; a1.z += w1 * v.z; a1.w += w1 * v.w;
      a2.x += w2 * v.x; a2.y += w2 * v.y; a2.z += w2 * v.z; a2.w += w2 * v.w;
    }
    __syncthreads();
  }
  for (int off = 32; off; off >>= 1) {
    p0 += __shfl_down(p0, off);
    p1 += __shfl_down(p1, off);
    p2 += __shfl_down(p2, off);
  }
  int wv = t >> 6, ln = t & 63;
  if (ln == 0) { red[wv * 3 + 0] = p0; red[wv * 3 + 1] = p1; red[wv * 3 + 2] = p2; }
  accbuf[0][g][dq] = a0;
  accbuf[1][g][dq] = a1;
  accbuf[2][g][dq] = a2;
  __syncthreads();
  if (t < 96) {
    int h = t >> 5, d = t & 31;
    float4 s0 = accbuf[h][0][d], s1 = accbuf[h][1][d], s2 = accbuf[h][2][d], s3 = accbuf[h][3][d];
    float dn = red[h] + red[3 + h];
    float inv = dn > 0.f ? 1.f / dn : 0.f;
    float4 r;
    r.x = (s0.x + s1.x + s2.x + s3.x) * inv;
    r.y = (s0.y + s1.y + s2.y + s3.y) * inv;
    r.z = (s0.z + s1.z + s2.z + s3.z) * inv;
    r.w = (s0.w + s1.w + s2.w + s3.w) * inv;
    *(float4*)&aggx[(size_t)n * 384 + h * 128 + d * 4] = r;
  }
}

// ---------------- GEMM: 128 rows x 64 cols per block, 256 threads,
// 2x16 microtile with SGPR-resident B ----------------
// Rounds 5/7 post-mortem: 8x8 microtile (acc 64 + fa 32 + prefetch 32 VGPRs)
// spilled to scratch (WRITE_SIZE 73 MB -> 440 MB vs 31 ideal); the "45% VALU"
// was half spill-addressing. This design removes B from BOTH the LDS bus and
// the VGPR file: each wave owns 16 cols, w is forced wave-uniform via
// __builtin_amdgcn_readfirstlane -> the B pointer is uniform -> compiler emits
// scalar loads into SGPRs (scalar pipe, free) and v_fmac with an SGPR operand.
// Per-thread: acc 2x16 = 32 VGPRs, fa 8, A-prefetch 16 -> ~70 total: no spill.
// LDS holds only A (18 KB, pad-9): per-32k-tile a wave issues 16 ds_read_b128
// (bank-balanced, bus-floor) = 25% of the 2048-cyc compute -> VALU ceiling ~100%
// (vs 33%/20%/67% of the previous structures).
// __launch_bounds__(256,4): 4 blocks/CU resident; single-buffer stage loop with
// register prefetch of the next A tile (round-3 pattern, proven spill-free).
// Both GEMMs: 942 blocks (NCB=6). GEMM1: cb = col-block (head = cb>>1).
// GEMM2 SPLIT: ks = cb>>1 (K-slice x3), nb = cb&1 (col-block); partials into
// fpart, combined in att_combine_kernel.

template <int NCB, bool SPLIT, bool BIAS_ELU>
__launch_bounds__(256, 4)
__global__ void gemm_sgprB_kernel(const float* __restrict__ A, int lda,
                                  const float* __restrict__ B, int ldb,
                                  float* __restrict__ C, int ldc,
                                  const float* __restrict__ bias) {
  __shared__ float4 As4[128 * 9];  // [r*9 + q], 18 KB
  int t = threadIdx.x;
  int lane = t & 63;
  int w = t >> 6;  // wave id 0..3

  // bijective XCD-chunk swizzle: consecutive logical tiles -> same XCD L2.
  constexpr int NROWT = 157;  // ceil(20000/128)
  constexpr int NWG = NROWT * NCB;
  constexpr int QW = NWG >> 3, RW = NWG & 7;
  int o = blockIdx.x;
  int xcd = o & 7, i8 = o >> 3;
  int wgid = (xcd < RW ? xcd * (QW + 1) : RW * (QW + 1) + (xcd - RW) * QW) + i8;
  int rt = wgid / NCB, cb = wgid - rt * NCB;
  int m0 = rt * 128;

  const float* Ab = A + (size_t)((cb >> 1) * 128);  // GEMM1: head slice; GEMM2: K-slice
  const float* Bb = SPLIT ? B + (size_t)((cb >> 1) * 128) * ldb + (cb & 1) * 64
                          : B + cb * 64;
  float* Cb = SPLIT ? C + (size_t)(cb >> 1) * NN * ldc + (cb & 1) * 64
                    : C + cb * 64;

  // wave-uniform B pointer -> scalar (SGPR) loads
  int wu = __builtin_amdgcn_readfirstlane(w);
  const float* Bw = Bb + wu * 16;

  // A staging geometry: thread stages 4 float4; idx = p*256+t, r = idx>>3, q = idx&7
  const float* sA[4];
  int dA[4];
#pragma unroll
  for (int p = 0; p < 4; ++p) {
    int idx = p * 256 + t;
    int r = idx >> 3, q = idx & 7;
    int row = m0 + r;
    if (row >= NN) row = NN - 1;  // tail tile: clamp (stores guarded)
    sA[p] = Ab + (size_t)row * lda + q * 4;
    dA[p] = r * 9 + q;
  }

  float acc0[16], acc1[16];
#pragma unroll
  for (int c = 0; c < 16; ++c) { acc0[c] = 0.f; acc1[c] = 0.f; }

  // prologue: prefetch tile 0
  float4 pa[4];
#pragma unroll
  for (int p = 0; p < 4; ++p) pa[p] = *(const float4*)sA[p];

  for (int k0 = 0; k0 < 128; k0 += 32) {
#pragma unroll
    for (int p = 0; p < 4; ++p) As4[dA[p]] = pa[p];
    __syncthreads();
    if (k0 + 32 < 128) {
#pragma unroll
      for (int p = 0; p < 4; ++p) pa[p] = *(const float4*)(sA[p] + k0 + 32);
    }
#pragma unroll
    for (int q = 0; q < 8; ++q) {
      float4 fa0 = As4[lane * 9 + q];         // A[m0+lane][k0+q*4 ..+3]
      float4 fa1 = As4[(lane + 64) * 9 + q];  // A[m0+lane+64][...]
      float a0f[4] = {fa0.x, fa0.y, fa0.z, fa0.w};
      float a1f[4] = {fa1.x, fa1.y, fa1.z, fa1.w};
#pragma unroll
      for (int j = 0; j < 4; ++j) {
        const float* Bk = Bw + (size_t)(k0 + q * 4 + j) * ldb;  // uniform
        float a0 = a0f[j], a1 = a1f[j];
#pragma unroll
        for (int c = 0; c < 16; ++c) {
          float bv = Bk[c];  // scalar load (SGPR): wave-uniform address
          acc0[c] += a0 * bv;
          acc1[c] += a1 * bv;
        }
      }
    }
    __syncthreads();
  }

  int colv = (SPLIT ? (cb & 1) * 64 : cb * 64) + w * 16;  // per-lane C addressing
#pragma unroll
  for (int rr = 0; rr < 2; ++rr) {
    int row = m0 + lane + rr * 64;
    if (row < NN) {
      float* Cr = Cb + (size_t)row * ldc + w * 16;
      const float* av = rr ? acc1 : acc0;
#pragma unroll
      for (int cc = 0; cc < 4; ++cc) {
        float4 v = make_float4(av[cc * 4 + 0], av[cc * 4 + 1],
                               av[cc * 4 + 2], av[cc * 4 + 3]);
        if (BIAS_ELU) {
          const float* bp = bias + cb * 64 + w * 16 + cc * 4;
          v.x += bp[0]; v.y += bp[1]; v.z += bp[2]; v.w += bp[3];
          v.x = v.x > 0.f ? v.x : expm1f(v.x);
          v.y = v.y > 0.f ? v.y : expm1f(v.y);
          v.z = v.z > 0.f ? v.z : expm1f(v.z);
          v.w = v.w > 0.f ? v.w : expm1f(v.w);
        }
        *(float4*)(Cr + cc * 4) = v;
      }
    }
  }
  (void)colv;
}

// ---------------- combine K-split partials + attention coefficients (layer 2) ----

__global__ void att_combine_kernel(const float* __restrict__ fp, const float* __restrict__ al,
                                   const float* __restrict__ ar, float* __restrict__ f2,
                                   float* __restrict__ el, float* __restrict__ er, int N) {
  int w = (blockIdx.x * 256 + threadIdx.x) >> 6;
  int lane = threadIdx.x & 63;
  if (w >= N) return;
  size_t base = (size_t)w * 128;
  const size_t PS = (size_t)NN * 128;
  float v0 = fp[base + lane] + fp[PS + base + lane] + fp[2 * PS + base + lane];
  float v1 = fp[base + 64 + lane] + fp[PS + base + 64 + lane] + fp[2 * PS + base + 64 + lane];
  f2[base + lane] = v0;
  f2[base + 64 + lane] = v1;
  float se = v0 * al[lane] + v1 * al[64 + lane];
  float sr = v0 * ar[lane] + v1 * ar[64 + lane];
  for (int off = 32; off; off >>= 1) {
    se += __shfl_down(se, off);
    sr += __shfl_down(sr, off);
  }
  if (lane == 0) { el[w] = se; er[w] = sr; }
}

// ---------------- layer-2 aggregation (H=1, gathers f2) ----------------

__global__ void aggregate1_kernel(const float* __restrict__ f, const float* __restrict__ el,
                                  const float* __restrict__ er, const float* __restrict__ bias,
                                  const int* __restrict__ rowptr, const int* __restrict__ csr_src,
                                  float* __restrict__ out) {
  int n = blockIdx.x;
  int t = threadIdx.x;
  __shared__ float wbuf[128];
  __shared__ int sbuf[128];
  __shared__ float red[2];
  __shared__ float4 accbuf[4][32];
  int rs = rowptr[n];
  int deg = rowptr[n + 1] - rs;
  float ern = er[n];
  float psum = 0.f;
  int g = t >> 5;
  int d = (t & 31) * 4;
  const float* fd = f + d;
  float4 acc = make_float4(0.f, 0.f, 0.f, 0.f);
  for (int base = 0; base < deg; base += 128) {
    int cnt = min(128, deg - base);
    if (t < cnt) {
      int s = csr_src[rs + base + t];
      sbuf[t] = s;
      float e = el[s] + ern;
      e = e > 0.f ? e : 0.2f * e;
      float w = __expf(e);
      wbuf[t] = w;
      psum += w;
    }
    __syncthreads();
    int j = g;
    for (; j + 4 < cnt; j += 8) {
      int s0 = sbuf[j], s1 = sbuf[j + 4];
      float4 v0 = *(const float4*)(fd + (size_t)s0 * 128);
      float4 v1 = *(const float4*)(fd + (size_t)s1 * 128);
      float w0 = wbuf[j], w1 = wbuf[j + 4];
      acc.x += w0 * v0.x + w1 * v1.x;
      acc.y += w0 * v0.y + w1 * v1.y;
      acc.z += w0 * v0.z + w1 * v1.z;
      acc.w += w0 * v0.w + w1 * v1.w;
    }
    for (; j < cnt; j += 4) {
      int s = sbuf[j];
      float4 v = *(const float4*)(fd + (size_t)s * 128);
      float w = wbuf[j];
      acc.x += w * v.x; acc.y += w * v.y; acc.z += w * v.z; acc.w += w * v.w;
    }
    __syncthreads();
  }
  for (int off = 32; off; off >>= 1) psum += __shfl_down(psum, off);
  int wv = t >> 6, ln = t & 63;
  if (ln == 0) red[wv] = psum;
  accbuf[g][t & 31] = acc;
  __syncthreads();
  if (t < 32) {
    float4 a0 = accbuf[0][t], a1 = accbuf[1][t], a2 = accbuf[2][t], a3 = accbuf[3][t];
    float dn = red[0] + red[1];
    float inv = dn > 0.f ? 1.f / dn : 0.f;
    const float* bp = bias + t * 4;
    float4 r;
    r.x = (a0.x + a1.x + a2.x + a3.x) * inv + bp[0];
    r.y = (a0.y + a1.y + a2.y + a3.y) * inv + bp[1];
    r.z = (a0.z + a1.z + a2.z + a3.z) * inv + bp[2];
    r.w = (a0.w + a1.w + a2.w + a3.w) * inv + bp[3];
    *(float4*)&out[(size_t)n * 128 + t * 4] = r;
  }
}

// ---------------- mean-pool: 2-stage ----------------

__global__ void pool_partial_kernel(const float* __restrict__ h2, const int* __restrict__ gid,
                                    float* __restrict__ sums, int N) {
  int g = blockIdx.x / PSPLIT;
  int sp = blockIdx.x % PSPLIT;
  int tid = threadIdx.x;
  int lo0 = 0, hi0 = N;
  while (lo0 < hi0) { int m = (lo0 + hi0) >> 1; if (gid[m] < g) lo0 = m + 1; else hi0 = m; }
  int lo1 = lo0, hi1 = N;
  while (lo1 < hi1) { int m = (lo1 + hi1) >> 1; if (gid[m] < g + 1) lo1 = m + 1; else hi1 = m; }
  float a0 = 0.f, a1 = 0.f, a2 = 0.f, a3 = 0.f;
  int n = lo0 + sp;
  for (; n + 3 * PSPLIT < lo1; n += 4 * PSPLIT) {
    a0 += h2[(size_t)n * 128 + tid];
    a1 += h2[(size_t)(n + PSPLIT) * 128 + tid];
    a2 += h2[(size_t)(n + 2 * PSPLIT) * 128 + tid];
    a3 += h2[(size_t)(n + 3 * PSPLIT) * 128 + tid];
  }
  for (; n < lo1; n += PSPLIT) a0 += h2[(size_t)n * 128 + tid];
  float acc = (a0 + a1) + (a2 + a3);
  atomicAdd(&sums[g * 128 + tid], acc);
}

__global__ void pool_final_kernel(const float* __restrict__ sums, const int* __restrict__ gid,
                                  const float* __restrict__ linW, const float* __restrict__ linb,
                                  float* __restrict__ out, int N) {
  int g = blockIdx.x;
  int tid = threadIdx.x;
  int lo0 = 0, hi0 = N;
  while (lo0 < hi0) { int m = (lo0 + hi0) >> 1; if (gid[m] < g) lo0 = m + 1; else hi0 = m; }
  int lo1 = lo0, hi1 = N;
  while (lo1 < hi1) { int m = (lo1 + hi1) >> 1; if (gid[m] < g + 1) lo1 = m + 1; else hi1 = m; }
  int cnt = lo1 - lo0;
  float hg = sums[g * 128 + tid] / (float)(cnt > 0 ? cnt : 1);
  __shared__ float hgs[128];
  hgs[tid] = hg;
  __syncthreads();
  float o = linb[tid];
#pragma unroll 4
  for (int dd = 0; dd < 128; dd++) o += hgs[dd] * linW[dd * 128 + tid];
  out[g * 128 + tid] = fmaxf(o, 0.f);
}

// ---------------- launch ----------------

extern "C" void kernel_launch(void* const* d_in, const int* in_sizes, int n_in,
                              void* d_out, int out_size, void* d_ws, size_t ws_size,
                              hipStream_t stream) {
  const float* x    = (const float*)d_in[0];
  const int*   src  = (const int*)d_in[1];
  const int*   dst  = (const int*)d_in[2];
  const int*   gid  = (const int*)d_in[3];
  const float* W1   = (const float*)d_in[4];
  const float* al1  = (const float*)d_in[5];
  const float* ar1  = (const float*)d_in[6];
  const float* b1   = (const float*)d_in[7];
  const float* W2   = (const float*)d_in[8];
  const float* al2  = (const float*)d_in[9];
  const float* ar2  = (const float*)d_in[10];
  const float* b2   = (const float*)d_in[11];
  const float* linW = (const float*)d_in[12];
  const float* linb = (const float*)d_in[13];
  float* out = (float*)d_out;

  char* ws = (char*)d_ws;
  size_t off = 0;
  auto alloc = [&](size_t bytes) -> void* {
    void* p = ws + off;
    off += (bytes + 255) & ~(size_t)255;
    return p;
  };
  float* aggx    = (float*)alloc((size_t)NN * 384 * 4);  // reused as fpart (3x NN*128) after GEMM1
  float* h1      = (float*)alloc((size_t)NN * 384 * 4);
  float* f2      = (float*)alloc((size_t)NN * 128 * 4);
  float* h2      = (float*)alloc((size_t)NN * 128 * 4);
  float* el1     = (float*)alloc((size_t)NN * 3 * 4);
  float* er1     = (float*)alloc((size_t)NN * 3 * 4);
  float* el2     = (float*)alloc((size_t)NN * 4);
  float* er2     = (float*)alloc((size_t)NN * 4);
  float* wlr     = (float*)alloc((size_t)768 * 4);
  int*   rowptr  = (int*)alloc((size_t)(NN + 1) * 4);
  int*   csr_src = (int*)alloc((size_t)NE * 4);
  int*   bsum    = (int*)alloc((size_t)NSCANB * 4);
  int*   boff    = (int*)alloc((size_t)NSCANB * 4);
  // zero-initialized region (single memset): indeg, cursor, gsums
  int*   indeg   = (int*)alloc((size_t)NN * 4);
  int*   cursor  = (int*)alloc((size_t)NN * 4);
  float* gsums   = (float*)alloc((size_t)NG * 128 * 4);
  (void)ws_size;
  size_t zbytes = (char*)(gsums + NG * 128) - (char*)indeg;
  hipMemsetAsync(indeg, 0, zbytes, stream);

  // CSR build (hierarchical scan)
  hist_kernel<<<(NE + 255) / 256, 256, 0, stream>>>(dst, indeg, NE);
  scan1_kernel<<<NSCANB, 256, 0, stream>>>(indeg, rowptr, bsum, NN);
  scan2_kernel<<<1, 128, 0, stream>>>(bsum, boff, rowptr + NN, NSCANB);
  scan3_kernel<<<NSCANB, 256, 0, stream>>>(rowptr, boff, NN);
  scatter_kernel<<<(NE + 255) / 256, 256, 0, stream>>>(src, dst, rowptr, cursor, csr_src, NE);

  // Layer 1 (x-space): wlr -> el/er -> aggregate x -> per-head GEMM with bias+ELU
  prep_wlr_kernel<<<3, 256, 0, stream>>>(W1, al1, ar1, wlr);
  elr_kernel<<<(NN + 3) / 4, 256, 0, stream>>>(x, wlr, el1, er1, NN);
  aggregate_x_kernel<<<NN, 128, 0, stream>>>(x, el1, er1, rowptr, csr_src, aggx);
  gemm_sgprB_kernel<6, false, true><<<157 * 6, 256, 0, stream>>>(
      aggx, 384, W1, 384, h1, 384, b1);

  // Layer 2: f2 = h1 @ W2 via K-split x3 (partials into fpart = reused aggx),
  // combined + el2/er2 in att_combine; aggregate(+b2) -> h2
  float* fpart = aggx;  // aggx dead after GEMM1; 3 * NN*128 floats fits exactly
  gemm_sgprB_kernel<6, true, false><<<157 * 6, 256, 0, stream>>>(
      h1, 384, W2, 128, fpart, 128, nullptr);
  att_combine_kernel<<<(NN + 3) / 4, 256, 0, stream>>>(fpart, al2, ar2, f2, el2, er2, NN);
  aggregate1_kernel<<<NN, 128, 0, stream>>>(f2, el2, er2, b2, rowptr, csr_src, h2);

  // Mean-pool + linear head
  pool_partial_kernel<<<NG * PSPLIT, 128, 0, stream>>>(h2, gid, gsums, NN);
  pool_final_kernel<<<NG, 128, 0, stream>>>(gsums, gid, linW, linb, out, NN);
}

// Round 9
// 307.512 us; speedup vs baseline: 1.7019x; 1.0177x over previous
//
#include <hip/hip_runtime.h>
#include <hip/hip_bf16.h>

#define NN 20000
#define NE 320000
#define NG 16
#define PSPLIT 32
#define NSCANB 79  // ceil(20000/256)

// ---------------- CSR build ----------------

__global__ void hist_kernel(const int* __restrict__ dst, int* __restrict__ indeg, int E) {
  int e = blockIdx.x * 256 + threadIdx.x;
  if (e < E) atomicAdd(&indeg[dst[e]], 1);
}

// hierarchical exclusive scan: per-block scan + block sums
__global__ void scan1_kernel(const int* __restrict__ in, int* __restrict__ outp,
                             int* __restrict__ bsum, int n) {
  int b = blockIdx.x, t = threadIdx.x;
  int i = b * 256 + t;
  int lane = t & 63, wv = t >> 6;
  __shared__ int ws[4];
  int v = (i < n) ? in[i] : 0;
  int x = v;
#pragma unroll
  for (int off = 1; off < 64; off <<= 1) {
    int y = __shfl_up(x, off);
    if (lane >= off) x += y;
  }
  if (lane == 63) ws[wv] = x;
  __syncthreads();
  int add = 0;
  for (int w2 = 0; w2 < wv; w2++) add += ws[w2];
  x += add;
  if (i < n) outp[i] = x - v;  // block-local exclusive
  if (t == 255) bsum[b] = x;   // block total
}

// scan block sums (nb <= 128), write offsets + grand total to rowptr[NN]
__global__ void scan2_kernel(const int* __restrict__ bsum, int* __restrict__ boff,
                             int* __restrict__ rp_end, int nb) {
  int t = threadIdx.x;  // 128
  int lane = t & 63, wv = t >> 6;
  __shared__ int ws[2];
  int v = (t < nb) ? bsum[t] : 0;
  int x = v;
#pragma unroll
  for (int off = 1; off < 64; off <<= 1) {
    int y = __shfl_up(x, off);
    if (lane >= off) x += y;
  }
  if (lane == 63) ws[wv] = x;
  __syncthreads();
  if (wv == 1) x += ws[0];
  if (t < nb) boff[t] = x - v;
  if (t == 127) *rp_end = x;
}

__global__ void scan3_kernel(int* __restrict__ outp, const int* __restrict__ boff, int n) {
  int i = blockIdx.x * 256 + threadIdx.x;
  if (i < n) outp[i] += boff[blockIdx.x];
}

__global__ void scatter_kernel(const int* __restrict__ src, const int* __restrict__ dst,
                               const int* __restrict__ rowptr, int* __restrict__ cursor,
                               int* __restrict__ csr_src, int E) {
  int e = blockIdx.x * 256 + threadIdx.x;
  if (e < E) {
    int d = dst[e];
    int p = atomicAdd(&cursor[d], 1);
    csr_src[rowptr[d] + p] = src[e];
  }
}

// ---------------- layer-1 attention vectors pushed through W1 ----------------

__global__ void prep_wlr_kernel(const float* __restrict__ W1, const float* __restrict__ al1,
                                const float* __restrict__ ar1, float* __restrict__ wlr) {
  int t = blockIdx.x * 256 + threadIdx.x;  // 768 total
  if (t >= 768) return;
  int k = t & 127;
  int j = t >> 7;  // 0..5
  int h = j % 3;
  const float* av = (j < 3 ? al1 : ar1) + h * 128;
  const float* wrow = W1 + (size_t)k * 384 + h * 128;
  float s = 0.f;
#pragma unroll 4
  for (int d = 0; d < 128; d++) s += wrow[d] * av[d];
  wlr[j * 128 + k] = s;
}

// el1/er1 for all nodes: one wave per node
__global__ void elr_kernel(const float* __restrict__ x, const float* __restrict__ wlr,
                           float* __restrict__ el, float* __restrict__ er, int N) {
  __shared__ float wl_s[768];
  int t = threadIdx.x;
  for (int i = t; i < 768; i += 256) wl_s[i] = wlr[i];
  __syncthreads();
  int w = (blockIdx.x * 256 + t) >> 6;
  int lane = t & 63;
  if (w >= N) return;
  float v0 = x[(size_t)w * 128 + lane], v1 = x[(size_t)w * 128 + 64 + lane];
  float s[6];
#pragma unroll
  for (int j = 0; j < 6; j++) s[j] = v0 * wl_s[j * 128 + lane] + v1 * wl_s[j * 128 + 64 + lane];
#pragma unroll
  for (int off = 32; off; off >>= 1)
#pragma unroll
    for (int j = 0; j < 6; j++) s[j] += __shfl_down(s[j], off);
  if (lane == 0) {
    el[w * 3 + 0] = s[0]; el[w * 3 + 1] = s[1]; el[w * 3 + 2] = s[2];
    er[w * 3 + 0] = s[3]; er[w * 3 + 1] = s[4]; er[w * 3 + 2] = s[5];
  }
}

// ---------------- layer-1 aggregation in x-space ----------------

__global__ void aggregate_x_kernel(const float* __restrict__ x, const float* __restrict__ el,
                                   const float* __restrict__ er, const int* __restrict__ rowptr,
                                   const int* __restrict__ csr_src, float* __restrict__ aggx) {
  int n = blockIdx.x;
  int t = threadIdx.x;  // 128
  __shared__ float wbuf[3][128];
  __shared__ int sbuf[128];
  __shared__ float red[6];
  __shared__ float4 accbuf[3][4][32];
  int rs = rowptr[n];
  int deg = rowptr[n + 1] - rs;
  float er0 = er[n * 3 + 0], er1 = er[n * 3 + 1], er2 = er[n * 3 + 2];
  float p0 = 0.f, p1 = 0.f, p2 = 0.f;
  int g = t >> 5, dq = t & 31;
  const float* xd = x + dq * 4;
  float4 a0 = make_float4(0, 0, 0, 0), a1 = a0, a2 = a0;
  for (int base = 0; base < deg; base += 128) {
    int cnt = min(128, deg - base);
    if (t < cnt) {
      int s = csr_src[rs + base + t];
      sbuf[t] = s;
      float e0 = el[s * 3 + 0] + er0, e1 = el[s * 3 + 1] + er1, e2 = el[s * 3 + 2] + er2;
      e0 = e0 > 0.f ? e0 : 0.2f * e0;
      e1 = e1 > 0.f ? e1 : 0.2f * e1;
      e2 = e2 > 0.f ? e2 : 0.2f * e2;
      float w0 = __expf(e0), w1 = __expf(e1), w2 = __expf(e2);
      wbuf[0][t] = w0; wbuf[1][t] = w1; wbuf[2][t] = w2;
      p0 += w0; p1 += w1; p2 += w2;
    }
    __syncthreads();
    int j = g;
    for (; j + 4 < cnt; j += 8) {
      int s0 = sbuf[j], s1 = sbuf[j + 4];
      float4 v0 = *(const float4*)(xd + (size_t)s0 * 128);
      float4 v1 = *(const float4*)(xd + (size_t)s1 * 128);
      float w00 = wbuf[0][j], w01 = wbuf[1][j], w02 = wbuf[2][j];
      float w10 = wbuf[0][j + 4], w11 = wbuf[1][j + 4], w12 = wbuf[2][j + 4];
      a0.x += w00 * v0.x + w10 * v1.x; a0.y += w00 * v0.y + w10 * v1.y;
      a0.z += w00 * v0.z + w10 * v1.z; a0.w += w00 * v0.w + w10 * v1.w;
      a1.x += w01 * v0.x + w11 * v1.x; a1.y += w01 * v0.y + w11 * v1.y;
      a1.z += w01 * v0.z + w11 * v1.z; a1.w += w01 * v0.w + w11 * v1.w;
      a2.x += w02 * v0.x + w12 * v1.x; a2.y += w02 * v0.y + w12 * v1.y;
      a2.z += w02 * v0.z + w12 * v1.z; a2.w += w02 * v0.w + w12 * v1.w;
    }
    for (; j < cnt; j += 4) {
      int s = sbuf[j];
      float4 v = *(const float4*)(xd + (size_t)s * 128);
      float w0 = wbuf[0][j], w1 = wbuf[1][j], w2 = wbuf[2][j];
      a0.x += w0 * v.x; a0.y += w0 * v.y; a0.z += w0 * v.z; a0.w += w0 * v.w;
      a1.x += w1 * v.x; a1.y += w1 * v.y; a1.z += w1 * v.z; a1.w += w1 * v.w;
      a2.x += w2 * v.x; a2.y += w2 * v.y; a2.z += w2 * v.z; a2.w += w2 * v.w;
    }
    __syncthreads();
  }
  for (int off = 32; off; off >>= 1) {
    p0 += __shfl_down(p0, off);
    p1 += __shfl_down(p1, off);
    p2 += __shfl_down(p2, off);
  }
  int wv = t >> 6, ln = t & 63;
  if (ln == 0) { red[wv * 3 + 0] = p0; red[wv * 3 + 1] = p1; red[wv * 3 + 2] = p2; }
  accbuf[0][g][dq] = a0;
  accbuf[1][g][dq] = a1;
  accbuf[2][g][dq] = a2;
  __syncthreads();
  if (t < 96) {
    int h = t >> 5, d = t & 31;
    float4 s0 = accbuf[h][0][d], s1 = accbuf[h][1][d], s2 = accbuf[h][2][d], s3 = accbuf[h][3][d];
    float dn = red[h] + red[3 + h];
    float inv = dn > 0.f ? 1.f / dn : 0.f;
    float4 r;
    r.x = (s0.x + s1.x + s2.x + s3.x) * inv;
    r.y = (s0.y + s1.y + s2.y + s3.y) * inv;
    r.z = (s0.z + s1.z + s2.z + s3.z) * inv;
    r.w = (s0.w + s1.w + s2.w + s3.w) * inv;
    *(float4*)&aggx[(size_t)n * 384 + h * 128 + d * 4] = r;
  }
}

// ---------------- GEMM: 128 rows x 64 cols per block, 256 threads,
// 2x16 microtile with SGPR-resident B ----------------
// Round-8 post-mortem: structure worked (SGPR B loads, 0 conflicts) but the
// epilogue's `const float* av = rr ? acc1 : acc0;` formed a runtime-selected
// POINTER to the local acc arrays -> compiler made them addressable -> scratch
// for the whole kernel (VGPR_Count 40, WRITE_SIZE 79 MB vs 31 ideal, VALU 42%).
// Fix (rule #20): epilogue duplicated per row with compile-time-static acc0/acc1
// accesses only. Everything else identical to round 8.
// Steady state per wave per 32-k tile: 1024 FMA-instr (2048 cyc) vs 16
// ds_read_b128 (192 cyc, 9%) + 32 uniform s_loads on the free scalar pipe.

template <int NCB, bool SPLIT, bool BIAS_ELU>
__launch_bounds__(256, 4)
__global__ void gemm_sgprB_kernel(const float* __restrict__ A, int lda,
                                  const float* __restrict__ B, int ldb,
                                  float* __restrict__ C, int ldc,
                                  const float* __restrict__ bias) {
  __shared__ float4 As4[128 * 9];  // [r*9 + q], 18 KB
  int t = threadIdx.x;
  int lane = t & 63;
  int w = t >> 6;  // wave id 0..3

  // bijective XCD-chunk swizzle: consecutive logical tiles -> same XCD L2.
  constexpr int NROWT = 157;  // ceil(20000/128)
  constexpr int NWG = NROWT * NCB;
  constexpr int QW = NWG >> 3, RW = NWG & 7;
  int o = blockIdx.x;
  int xcd = o & 7, i8 = o >> 3;
  int wgid = (xcd < RW ? xcd * (QW + 1) : RW * (QW + 1) + (xcd - RW) * QW) + i8;
  int rt = wgid / NCB, cb = wgid - rt * NCB;
  int m0 = rt * 128;

  const float* Ab = A + (size_t)((cb >> 1) * 128);  // GEMM1: head slice; GEMM2: K-slice
  const float* Bb = SPLIT ? B + (size_t)((cb >> 1) * 128) * ldb + (cb & 1) * 64
                          : B + cb * 64;
  float* Cb = SPLIT ? C + (size_t)(cb >> 1) * NN * ldc + (cb & 1) * 64
                    : C + cb * 64;

  // wave-uniform B pointer -> scalar (SGPR) loads
  int wu = __builtin_amdgcn_readfirstlane(w);
  const float* Bw = Bb + wu * 16;

  // A staging geometry: thread stages 4 float4; idx = p*256+t, r = idx>>3, q = idx&7
  const float* sA[4];
  int dA[4];
#pragma unroll
  for (int p = 0; p < 4; ++p) {
    int idx = p * 256 + t;
    int r = idx >> 3, q = idx & 7;
    int row = m0 + r;
    if (row >= NN) row = NN - 1;  // tail tile: clamp (stores guarded)
    sA[p] = Ab + (size_t)row * lda + q * 4;
    dA[p] = r * 9 + q;
  }

  float acc0[16], acc1[16];
#pragma unroll
  for (int c = 0; c < 16; ++c) { acc0[c] = 0.f; acc1[c] = 0.f; }

  // prologue: prefetch tile 0
  float4 pa[4];
#pragma unroll
  for (int p = 0; p < 4; ++p) pa[p] = *(const float4*)sA[p];

  for (int k0 = 0; k0 < 128; k0 += 32) {
#pragma unroll
    for (int p = 0; p < 4; ++p) As4[dA[p]] = pa[p];
    __syncthreads();
    if (k0 + 32 < 128) {
#pragma unroll
      for (int p = 0; p < 4; ++p) pa[p] = *(const float4*)(sA[p] + k0 + 32);
    }
#pragma unroll
    for (int q = 0; q < 8; ++q) {
      float4 fa0 = As4[lane * 9 + q];         // A[m0+lane][k0+q*4 ..+3]
      float4 fa1 = As4[(lane + 64) * 9 + q];  // A[m0+lane+64][...]
      float a0f[4] = {fa0.x, fa0.y, fa0.z, fa0.w};
      float a1f[4] = {fa1.x, fa1.y, fa1.z, fa1.w};
#pragma unroll
      for (int j = 0; j < 4; ++j) {
        const float* Bk = Bw + (size_t)(k0 + q * 4 + j) * ldb;  // uniform
        float a0 = a0f[j], a1 = a1f[j];
#pragma unroll
        for (int c = 0; c < 16; ++c) {
          float bv = Bk[c];  // scalar load (SGPR): wave-uniform address
          acc0[c] += a0 * bv;
          acc1[c] += a1 * bv;
        }
      }
    }
    __syncthreads();
  }

  // epilogue: compile-time-static acc indexing ONLY (no pointer select over
  // the acc arrays -- that was round-8's scratch-demotion bug).
  int row0 = m0 + lane;
  if (row0 < NN) {
    float* Cr = Cb + (size_t)row0 * ldc + w * 16;
#pragma unroll
    for (int cc = 0; cc < 4; ++cc) {
      float4 v = make_float4(acc0[cc * 4 + 0], acc0[cc * 4 + 1],
                             acc0[cc * 4 + 2], acc0[cc * 4 + 3]);
      if (BIAS_ELU) {
        const float* bp = bias + cb * 64 + w * 16 + cc * 4;
        v.x += bp[0]; v.y += bp[1]; v.z += bp[2]; v.w += bp[3];
        v.x = v.x > 0.f ? v.x : expm1f(v.x);
        v.y = v.y > 0.f ? v.y : expm1f(v.y);
        v.z = v.z > 0.f ? v.z : expm1f(v.z);
        v.w = v.w > 0.f ? v.w : expm1f(v.w);
      }
      *(float4*)(Cr + cc * 4) = v;
    }
  }
  int row1 = m0 + lane + 64;
  if (row1 < NN) {
    float* Cr = Cb + (size_t)row1 * ldc + w * 16;
#pragma unroll
    for (int cc = 0; cc < 4; ++cc) {
      float4 v = make_float4(acc1[cc * 4 + 0], acc1[cc * 4 + 1],
                             acc1[cc * 4 + 2], acc1[cc * 4 + 3]);
      if (BIAS_ELU) {
        const float* bp = bias + cb * 64 + w * 16 + cc * 4;
        v.x += bp[0]; v.y += bp[1]; v.z += bp[2]; v.w += bp[3];
        v.x = v.x > 0.f ? v.x : expm1f(v.x);
        v.y = v.y > 0.f ? v.y : expm1f(v.y);
        v.z = v.z > 0.f ? v.z : expm1f(v.z);
        v.w = v.w > 0.f ? v.w : expm1f(v.w);
      }
      *(float4*)(Cr + cc * 4) = v;
    }
  }
}

// ---------------- combine K-split partials + attention coefficients (layer 2) ----

__global__ void att_combine_kernel(const float* __restrict__ fp, const float* __restrict__ al,
                                   const float* __restrict__ ar, float* __restrict__ f2,
                                   float* __restrict__ el, float* __restrict__ er, int N) {
  int w = (blockIdx.x * 256 + threadIdx.x) >> 6;
  int lane = threadIdx.x & 63;
  if (w >= N) return;
  size_t base = (size_t)w * 128;
  const size_t PS = (size_t)NN * 128;
  float v0 = fp[base + lane] + fp[PS + base + lane] + fp[2 * PS + base + lane];
  float v1 = fp[base + 64 + lane] + fp[PS + base + 64 + lane] + fp[2 * PS + base + 64 + lane];
  f2[base + lane] = v0;
  f2[base + 64 + lane] = v1;
  float se = v0 * al[lane] + v1 * al[64 + lane];
  float sr = v0 * ar[lane] + v1 * ar[64 + lane];
  for (int off = 32; off; off >>= 1) {
    se += __shfl_down(se, off);
    sr += __shfl_down(sr, off);
  }
  if (lane == 0) { el[w] = se; er[w] = sr; }
}

// ---------------- layer-2 aggregation (H=1, gathers f2) ----------------

__global__ void aggregate1_kernel(const float* __restrict__ f, const float* __restrict__ el,
                                  const float* __restrict__ er, const float* __restrict__ bias,
                                  const int* __restrict__ rowptr, const int* __restrict__ csr_src,
                                  float* __restrict__ out) {
  int n = blockIdx.x;
  int t = threadIdx.x;
  __shared__ float wbuf[128];
  __shared__ int sbuf[128];
  __shared__ float red[2];
  __shared__ float4 accbuf[4][32];
  int rs = rowptr[n];
  int deg = rowptr[n + 1] - rs;
  float ern = er[n];
  float psum = 0.f;
  int g = t >> 5;
  int d = (t & 31) * 4;
  const float* fd = f + d;
  float4 acc = make_float4(0.f, 0.f, 0.f, 0.f);
  for (int base = 0; base < deg; base += 128) {
    int cnt = min(128, deg - base);
    if (t < cnt) {
      int s = csr_src[rs + base + t];
      sbuf[t] = s;
      float e = el[s] + ern;
      e = e > 0.f ? e : 0.2f * e;
      float w = __expf(e);
      wbuf[t] = w;
      psum += w;
    }
    __syncthreads();
    int j = g;
    for (; j + 4 < cnt; j += 8) {
      int s0 = sbuf[j], s1 = sbuf[j + 4];
      float4 v0 = *(const float4*)(fd + (size_t)s0 * 128);
      float4 v1 = *(const float4*)(fd + (size_t)s1 * 128);
      float w0 = wbuf[j], w1 = wbuf[j + 4];
      acc.x += w0 * v0.x + w1 * v1.x;
      acc.y += w0 * v0.y + w1 * v1.y;
      acc.z += w0 * v0.z + w1 * v1.z;
      acc.w += w0 * v0.w + w1 * v1.w;
    }
    for (; j < cnt; j += 4) {
      int s = sbuf[j];
      float4 v = *(const float4*)(fd + (size_t)s * 128);
      float w = wbuf[j];
      acc.x += w * v.x; acc.y += w * v.y; acc.z += w * v.z; acc.w += w * v.w;
    }
    __syncthreads();
  }
  for (int off = 32; off; off >>= 1) psum += __shfl_down(psum, off);
  int wv = t >> 6, ln = t & 63;
  if (ln == 0) red[wv] = psum;
  accbuf[g][t & 31] = acc;
  __syncthreads();
  if (t < 32) {
    float4 a0 = accbuf[0][t], a1 = accbuf[1][t], a2 = accbuf[2][t], a3 = accbuf[3][t];
    float dn = red[0] + red[1];
    float inv = dn > 0.f ? 1.f / dn : 0.f;
    const float* bp = bias + t * 4;
    float4 r;
    r.x = (a0.x + a1.x + a2.x + a3.x) * inv + bp[0];
    r.y = (a0.y + a1.y + a2.y + a3.y) * inv + bp[1];
    r.z = (a0.z + a1.z + a2.z + a3.z) * inv + bp[2];
    r.w = (a0.w + a1.w + a2.w + a3.w) * inv + bp[3];
    *(float4*)&out[(size_t)n * 128 + t * 4] = r;
  }
}

// ---------------- mean-pool: 2-stage ----------------

__global__ void pool_partial_kernel(const float* __restrict__ h2, const int* __restrict__ gid,
                                    float* __restrict__ sums, int N) {
  int g = blockIdx.x / PSPLIT;
  int sp = blockIdx.x % PSPLIT;
  int tid = threadIdx.x;
  int lo0 = 0, hi0 = N;
  while (lo0 < hi0) { int m = (lo0 + hi0) >> 1; if (gid[m] < g) lo0 = m + 1; else hi0 = m; }
  int lo1 = lo0, hi1 = N;
  while (lo1 < hi1) { int m = (lo1 + hi1) >> 1; if (gid[m] < g + 1) lo1 = m + 1; else hi1 = m; }
  float a0 = 0.f, a1 = 0.f, a2 = 0.f, a3 = 0.f;
  int n = lo0 + sp;
  for (; n + 3 * PSPLIT < lo1; n += 4 * PSPLIT) {
    a0 += h2[(size_t)n * 128 + tid];
    a1 += h2[(size_t)(n + PSPLIT) * 128 + tid];
    a2 += h2[(size_t)(n + 2 * PSPLIT) * 128 + tid];
    a3 += h2[(size_t)(n + 3 * PSPLIT) * 128 + tid];
  }
  for (; n < lo1; n += PSPLIT) a0 += h2[(size_t)n * 128 + tid];
  float acc = (a0 + a1) + (a2 + a3);
  atomicAdd(&sums[g * 128 + tid], acc);
}

__global__ void pool_final_kernel(const float* __restrict__ sums, const int* __restrict__ gid,
                                  const float* __restrict__ linW, const float* __restrict__ linb,
                                  float* __restrict__ out, int N) {
  int g = blockIdx.x;
  int tid = threadIdx.x;
  int lo0 = 0, hi0 = N;
  while (lo0 < hi0) { int m = (lo0 + hi0) >> 1; if (gid[m] < g) lo0 = m + 1; else hi0 = m; }
  int lo1 = lo0, hi1 = N;
  while (lo1 < hi1) { int m = (lo1 + hi1) >> 1; if (gid[m] < g + 1) lo1 = m + 1; else hi1 = m; }
  int cnt = lo1 - lo0;
  float hg = sums[g * 128 + tid] / (float)(cnt > 0 ? cnt : 1);
  __shared__ float hgs[128];
  hgs[tid] = hg;
  __syncthreads();
  float o = linb[tid];
#pragma unroll 4
  for (int dd = 0; dd < 128; dd++) o += hgs[dd] * linW[dd * 128 + tid];
  out[g * 128 + tid] = fmaxf(o, 0.f);
}

// ---------------- launch ----------------

extern "C" void kernel_launch(void* const* d_in, const int* in_sizes, int n_in,
                              void* d_out, int out_size, void* d_ws, size_t ws_size,
                              hipStream_t stream) {
  const float* x    = (const float*)d_in[0];
  const int*   src  = (const int*)d_in[1];
  const int*   dst  = (const int*)d_in[2];
  const int*   gid  = (const int*)d_in[3];
  const float* W1   = (const float*)d_in[4];
  const float* al1  = (const float*)d_in[5];
  const float* ar1  = (const float*)d_in[6];
  const float* b1   = (const float*)d_in[7];
  const float* W2   = (const float*)d_in[8];
  const float* al2  = (const float*)d_in[9];
  const float* ar2  = (const float*)d_in[10];
  const float* b2   = (const float*)d_in[11];
  const float* linW = (const float*)d_in[12];
  const float* linb = (const float*)d_in[13];
  float* out = (float*)d_out;

  char* ws = (char*)d_ws;
  size_t off = 0;
  auto alloc = [&](size_t bytes) -> void* {
    void* p = ws + off;
    off += (bytes + 255) & ~(size_t)255;
    return p;
  };
  float* aggx    = (float*)alloc((size_t)NN * 384 * 4);  // reused as fpart (3x NN*128) after GEMM1
  float* h1      = (float*)alloc((size_t)NN * 384 * 4);
  float* f2      = (float*)alloc((size_t)NN * 128 * 4);
  float* h2      = (float*)alloc((size_t)NN * 128 * 4);
  float* el1     = (float*)alloc((size_t)NN * 3 * 4);
  float* er1     = (float*)alloc((size_t)NN * 3 * 4);
  float* el2     = (float*)alloc((size_t)NN * 4);
  float* er2     = (float*)alloc((size_t)NN * 4);
  float* wlr     = (float*)alloc((size_t)768 * 4);
  int*   rowptr  = (int*)alloc((size_t)(NN + 1) * 4);
  int*   csr_src = (int*)alloc((size_t)NE * 4);
  int*   bsum    = (int*)alloc((size_t)NSCANB * 4);
  int*   boff    = (int*)alloc((size_t)NSCANB * 4);
  // zero-initialized region (single memset): indeg, cursor, gsums
  int*   indeg   = (int*)alloc((size_t)NN * 4);
  int*   cursor  = (int*)alloc((size_t)NN * 4);
  float* gsums   = (float*)alloc((size_t)NG * 128 * 4);
  (void)ws_size;
  size_t zbytes = (char*)(gsums + NG * 128) - (char*)indeg;
  hipMemsetAsync(indeg, 0, zbytes, stream);

  // CSR build (hierarchical scan)
  hist_kernel<<<(NE + 255) / 256, 256, 0, stream>>>(dst, indeg, NE);
  scan1_kernel<<<NSCANB, 256, 0, stream>>>(indeg, rowptr, bsum, NN);
  scan2_kernel<<<1, 128, 0, stream>>>(bsum, boff, rowptr + NN, NSCANB);
  scan3_kernel<<<NSCANB, 256, 0, stream>>>(rowptr, boff, NN);
  scatter_kernel<<<(NE + 255) / 256, 256, 0, stream>>>(src, dst, rowptr, cursor, csr_src, NE);

  // Layer 1 (x-space): wlr -> el/er -> aggregate x -> per-head GEMM with bias+ELU
  prep_wlr_kernel<<<3, 256, 0, stream>>>(W1, al1, ar1, wlr);
  elr_kernel<<<(NN + 3) / 4, 256, 0, stream>>>(x, wlr, el1, er1, NN);
  aggregate_x_kernel<<<NN, 128, 0, stream>>>(x, el1, er1, rowptr, csr_src, aggx);
  gemm_sgprB_kernel<6, false, true><<<157 * 6, 256, 0, stream>>>(
      aggx, 384, W1, 384, h1, 384, b1);

  // Layer 2: f2 = h1 @ W2 via K-split x3 (partials into fpart = reused aggx),
  // combined + el2/er2 in att_combine; aggregate(+b2) -> h2
  float* fpart = aggx;  // aggx dead after GEMM1; 3 * NN*128 floats fits exactly
  gemm_sgprB_kernel<6, true, false><<<157 * 6, 256, 0, stream>>>(
      h1, 384, W2, 128, fpart, 128, nullptr);
  att_combine_kernel<<<(NN + 3) / 4, 256, 0, stream>>>(fpart, al2, ar2, f2, el2, er2, NN);
  aggregate1_kernel<<<NN, 128, 0, stream>>>(f2, el2, er2, b2, rowptr, csr_src, h2);

  // Mean-pool + linear head
  pool_partial_kernel<<<NG * PSPLIT, 128, 0, stream>>>(h2, gid, gsums, NN);
  pool_final_kernel<<<NG, 128, 0, stream>>>(gsums, gid, linW, linb, out, NN);
}